// Round 17
// baseline (551.950 us; speedup 1.0000x reference)
//
#include <hip/hip_runtime.h>
#include <math.h>

#define NB    8
#define IMG   224
#define NTOK  (IMG*IMG)          // 50176 per batch
#define DIM   96
#define INR   128
#define HIDN  384
#define WT    49
#define SCALE 0.17677669529663687f
#define QKS   72                 // qk LDS row stride (shorts): q cols 0..31, k cols 32..63
#define OSS   136                // os row stride (shorts)
#define TSS   200                // ts row stride (shorts)

typedef __attribute__((ext_vector_type(8))) short bf16x8;
typedef __attribute__((ext_vector_type(4))) float f32x4;
typedef __attribute__((ext_vector_type(4))) unsigned int u32x4;

#define MFMA16(a,b,c) __builtin_amdgcn_mfma_f32_16x16x32_bf16((a),(b),(c),0,0,0)

__device__ __forceinline__ short f2bf(float f) {
    unsigned u = __builtin_bit_cast(unsigned, f);
    u += 0x7fffu + ((u >> 16) & 1u);
    return (short)(u >> 16);
}

// truncating pack of two f32 -> packed bf16x2 (lo in low 16)
__device__ __forceinline__ unsigned pktrunc(float lo, float hi) {
    return (__builtin_bit_cast(unsigned, hi) & 0xFFFF0000u) |
           (__builtin_bit_cast(unsigned, lo) >> 16);
}

// tanh-form GELU
__device__ __forceinline__ float gelu_f(float z) {
    const float u = z * 1.5957691216057308f * fmaf(0.044715f * z, z, 1.f);
    return z / (1.f + __expf(-u));
}

// fragment-major weight load: wave reads contiguous 1KB (tile*1024B + lane*16B)
__device__ __forceinline__ bf16x8 ldfrag(const short* base, int tile, int lane) {
    return *reinterpret_cast<const bf16x8*>(base + ((tile << 6) + lane) * 8);
}

// ---------- prep: weights -> bf16 in FRAGMENT-MAJOR layout; rel bias gathered ----------
__global__ void prep_kernel(const float* __restrict__ wqkv, const float* __restrict__ wout,
                            const float* __restrict__ w1,   const float* __restrict__ w2,
                            const float* __restrict__ rel_bias, char* __restrict__ ws)
{
    short* wqkvb = (short*)ws;                 // 36864 elems, tiles r<24, c<3
    short* woutb = (short*)(ws + 73728);       // 12288, tiles r<6, c<4
    short* w1b   = (short*)(ws + 98304);       // 36864, tiles r<24, c<3
    short* w2b   = (short*)(ws + 172032);      // 36864, tiles r<6, c<12
    float* biasp = (float*)(ws + 245760);      // [4][49][64] fp32, pre-scaled, key-padded
    const int idx = blockIdx.x * 256 + threadIdx.x;
    if (idx < 36864) {
        const int tile = idx >> 9, lane = (idx >> 3) & 63, j = idx & 7;
        const int r = tile / 3, c = tile % 3;
        wqkvb[idx] = f2bf(wqkv[(r*16 + (lane & 15))*96 + c*32 + (lane >> 4)*8 + j]);
    } else if (idx < 49152) {
        const int t = idx - 36864;
        const int tile = t >> 9, lane = (t >> 3) & 63, j = t & 7;
        const int r = tile >> 2, c = tile & 3;
        woutb[t] = f2bf(wout[(r*16 + (lane & 15))*128 + c*32 + (lane >> 4)*8 + j]);
    } else if (idx < 86016) {
        const int t = idx - 49152;
        const int tile = t >> 9, lane = (t >> 3) & 63, j = t & 7;
        const int r = tile / 3, c = tile % 3;
        w1b[t] = f2bf(w1[(r*16 + (lane & 15))*96 + c*32 + (lane >> 4)*8 + j]);
    } else if (idx < 122880) {
        const int t = idx - 86016;
        const int tile = t >> 9, lane = (t >> 3) & 63, j = t & 7;
        const int r = tile / 12, c = tile % 12;
        w2b[t] = f2bf(w2[(r*16 + (lane & 15))*384 + c*32 + (lane >> 4)*8 + j]);
    } else if (idx < 135424) {
        const int t = idx - 122880;
        const int h = t / 3136, r = t % 3136, q = r / 64, k = r % 64;
        float v = 0.f;
        if (k < 49) {
            const int rel = (q/7 - k/7 + 6) * 13 + (q%7 - k%7 + 6);
            v = rel_bias[rel * 4 + h] * SCALE;
        }
        biasp[t] = v;
    }
}

// ---------- fused kernel: 4 blocks/CU attempt ----------
// LDS pool (38912 B), R9-style aliasing (4 x 38912 = 155648 <= 163840 -> 4 blocks/CU):
//   hs[64][104]        [0,13312)
//   qk[4][64][QKS]     [0,36864)     ALIASES hs -> barrier b2 between hs-reads and qk-stores
//   os[64][OSS]        [13312,30720) (aliases qk waves>=1; gated by b3)
//   h2[64][104]        [0,13312)     (aliases hs + qk wave0; gated by b4)
//   ts[64][TSS]        [13312,38912) (aliases os; gated by b6)
// Register diet for the (256,4) 128-VGPR budget: single-pass qkv (~115 peak),
// NO wofr prefetch (R14), b1/b2 biases loaded inline. If this spills, WRITE_SIZE
// blows past 250MB (recognizable) and we revert to R16.
__global__ __launch_bounds__(256, 4) void fused_kernel(
    const float* __restrict__ x, const char* __restrict__ ws,
    const float* __restrict__ b_out, const float* __restrict__ ln1_g,
    const float* __restrict__ ln1_b, const float* __restrict__ ln2_g,
    const float* __restrict__ ln2_b, const float* __restrict__ b1,
    const float* __restrict__ b2, float* __restrict__ y)
{
    __shared__ __align__(16) char pool[38912];
    short* hs = (short*)pool;
    short* qk = (short*)pool;              // aliases hs
    short* os = (short*)(pool + 13312);
    short* h2 = (short*)pool;
    short* ts = (short*)(pool + 13312);

    const short* wqkvb = (const short*)ws;
    const short* woutb = (const short*)(ws + 73728);
    const short* w1b   = (const short*)(ws + 98304);
    const short* w2b   = (const short*)(ws + 172032);
    const float* biasp = (const float*)(ws + 245760);

    const int tid = threadIdx.x;
    const int wv  = tid >> 6;         // wave = head (attn) / M-tile (proj,FFN)
    const int lane = tid & 63;
    const int l15 = tid & 15;
    const int l4  = (tid & 63) >> 4;
    const int wid = blockIdx.x;
    const int b = wid >> 10, xr = (wid >> 5) & 31, yr = wid & 31;
    const int qkbase = wv * 64 * QKS;

    // ---- LN1: 4 threads per row ----
    if (tid < 196) {
        const int i = tid >> 2, g = tid & 3;
        const float* xp = x + ((size_t)b * NTOK + (size_t)(xr*7 + i/7) * IMG + (yr*7 + i%7)) * DIM + g*24;
        float v[24]; float s = 0.f, s2 = 0.f;
        #pragma unroll
        for (int c = 0; c < 6; ++c) {
            const float4 t4 = *reinterpret_cast<const float4*>(xp + c*4);
            v[c*4+0]=t4.x; v[c*4+1]=t4.y; v[c*4+2]=t4.z; v[c*4+3]=t4.w;
            s  += t4.x + t4.y + t4.z + t4.w;
            s2 += t4.x*t4.x + t4.y*t4.y + t4.z*t4.z + t4.w*t4.w;
        }
        s  += __shfl_xor(s, 1);  s  += __shfl_xor(s, 2);
        s2 += __shfl_xor(s2, 1); s2 += __shfl_xor(s2, 2);
        const float mu = s * (1.f/96.f);
        const float rs = rsqrtf(s2 * (1.f/96.f) - mu*mu + 1e-5f);
        #pragma unroll
        for (int c = 0; c < 24; ++c) {
            const int d = g*24 + c;
            hs[i*104 + d] = f2bf((v[c] - mu) * rs * ln1_g[d] + ln1_b[d]);
        }
    }
    for (int idx = tid; idx < 15*104; idx += 256) hs[49*104 + idx] = 0;
    __syncthreads();   // b1: hs ready

    // ---- qkv GEMM, single pass (R9/R11-proven), head-partitioned ----
    u32x4 vfrag[2][2];   // V packed bf16, PV A-operand (regs only)
    {
        f32x4 acc[6][4];
        #pragma unroll
        for (int nt = 0; nt < 6; ++nt)
            #pragma unroll
            for (int mt = 0; mt < 4; ++mt)
                acc[nt][mt] = (f32x4){0.f,0.f,0.f,0.f};
        #pragma unroll
        for (int k3 = 0; k3 < 3; ++k3) {
            bf16x8 a4[4];
            #pragma unroll
            for (int mt = 0; mt < 4; ++mt)
                a4[mt] = *reinterpret_cast<const bf16x8*>(&hs[(mt*16 + l15)*104 + k3*32 + l4*8]);
            #pragma unroll
            for (int nt = 0; nt < 6; ++nt) {
                const int r = (nt < 2 ? wv*2 + nt
                              : nt < 4 ? 8 + wv*2 + (nt-2)
                                       : 16 + wv*2 + (nt-4));
                const bf16x8 bfr = ldfrag(wqkvb, r*3 + k3, lane);
                #pragma unroll
                for (int mt = 0; mt < 4; ++mt)
                    acc[nt][mt] = MFMA16(a4[mt], bfr, acc[nt][mt]);
            }
        }
        __syncthreads();   // b2: all hs reads done; qk stores (aliasing hs) may proceed
        // q (cols 0..31), k (cols 32..63) -> wave-private LDS
        #pragma unroll
        for (int nt = 0; nt < 4; ++nt) {
            const int col0 = nt*16;
            #pragma unroll
            for (int mt = 0; mt < 4; ++mt)
                #pragma unroll
                for (int rg = 0; rg < 4; ++rg)
                    qk[qkbase + (mt*16 + l4*4 + rg)*QKS + col0 + l15] = f2bf(acc[nt][mt][rg]);
        }
        // v -> registers, permuted-k PV A-fragments
        #pragma unroll
        for (int md = 0; md < 2; ++md)
            #pragma unroll
            for (int kst = 0; kst < 2; ++kst)
                vfrag[md][kst] = (u32x4){
                    pktrunc(acc[4+md][2*kst  ][0], acc[4+md][2*kst  ][1]),
                    pktrunc(acc[4+md][2*kst  ][2], acc[4+md][2*kst  ][3]),
                    pktrunc(acc[4+md][2*kst+1][0], acc[4+md][2*kst+1][1]),
                    pktrunc(acc[4+md][2*kst+1][2], acc[4+md][2*kst+1][3])};
    }
    // no barrier: qk store->read is same-wave (wave-private region)

    // ---- S^T = K @ Q^T (wave = head, wave-private LDS reads) ----
    f32x4 st[4][4];    // [mtKey][ntQuery]
    {
        bf16x8 kf[4], qf[4];
        #pragma unroll
        for (int mt = 0; mt < 4; ++mt)
            kf[mt] = *reinterpret_cast<const bf16x8*>(&qk[qkbase + (mt*16 + l15)*QKS + 32 + l4*8]);
        #pragma unroll
        for (int nt = 0; nt < 4; ++nt)
            qf[nt] = *reinterpret_cast<const bf16x8*>(&qk[qkbase + (nt*16 + l15)*QKS + l4*8]);
        #pragma unroll
        for (int mt = 0; mt < 4; ++mt)
            #pragma unroll
            for (int nt = 0; nt < 4; ++nt)
                st[mt][nt] = MFMA16(kf[mt], qf[nt], ((f32x4){0.f,0.f,0.f,0.f}));
    }
    __syncthreads();   // b3: all qk reads done; os stores may clobber other waves' qk

    // ---- softmax over keys (in-lane 13 live + 2 shfl), pack P^T ----
    unsigned pk[4][4][2];   // [ntQuery][mtKey][pair]
    #pragma unroll
    for (int nq = 0; nq < 4; ++nq) {
        const int qc = (nq*16 + l15) < WT ? (nq*16 + l15) : 48;
        const float* bp = biasp + (wv*49 + qc)*64;
        float v[13];
        #pragma unroll
        for (int mk = 0; mk < 3; ++mk) {
            const float4 b4 = *reinterpret_cast<const float4*>(&bp[mk*16 + l4*4]);
            v[mk*4+0] = fmaf(st[mk][nq][0], SCALE, b4.x);
            v[mk*4+1] = fmaf(st[mk][nq][1], SCALE, b4.y);
            v[mk*4+2] = fmaf(st[mk][nq][2], SCALE, b4.z);
            v[mk*4+3] = fmaf(st[mk][nq][3], SCALE, b4.w);
        }
        v[12] = (l4 == 0) ? fmaf(st[3][nq][0], SCALE, bp[48]) : -1e30f;  // key 48
        float mx = v[0];
        #pragma unroll
        for (int t = 1; t < 13; ++t) mx = fmaxf(mx, v[t]);
        mx = fmaxf(mx, __shfl_xor(mx, 16));
        mx = fmaxf(mx, __shfl_xor(mx, 32));
        float sum = 0.f;
        #pragma unroll
        for (int t = 0; t < 13; ++t) { v[t] = __expf(v[t] - mx); sum += v[t]; }
        sum += __shfl_xor(sum, 16);
        sum += __shfl_xor(sum, 32);
        const float inv = 1.f / sum;
        #pragma unroll
        for (int mk = 0; mk < 3; ++mk) {
            pk[nq][mk][0] = pktrunc(v[mk*4+0]*inv, v[mk*4+1]*inv);
            pk[nq][mk][1] = pktrunc(v[mk*4+2]*inv, v[mk*4+3]*inv);
        }
        pk[nq][3][0] = pktrunc(v[12]*inv, 0.f);
        pk[nq][3][1] = 0u;
    }

    // ---- PV: o^T = V^T @ P^T — BOTH operands from registers ----
    {
        f32x4 oc[2][4];   // [mtDim][ntQuery]
        #pragma unroll
        for (int md = 0; md < 2; ++md)
            #pragma unroll
            for (int nq = 0; nq < 4; ++nq)
                oc[md][nq] = (f32x4){0.f,0.f,0.f,0.f};
        #pragma unroll
        for (int kst = 0; kst < 2; ++kst) {
            #pragma unroll
            for (int nq = 0; nq < 4; ++nq) {
                const bf16x8 bp8 = __builtin_bit_cast(bf16x8,
                    (u32x4){pk[nq][2*kst][0], pk[nq][2*kst][1], pk[nq][2*kst+1][0], pk[nq][2*kst+1][1]});
                #pragma unroll
                for (int md = 0; md < 2; ++md)
                    oc[md][nq] = MFMA16(__builtin_bit_cast(bf16x8, vfrag[md][kst]), bp8, oc[md][nq]);
            }
        }
        // os store (transpose back): os[query][inner]
        #pragma unroll
        for (int md = 0; md < 2; ++md)
            #pragma unroll
            for (int nq = 0; nq < 4; ++nq) {
                const unsigned lo = pktrunc(oc[md][nq][0], oc[md][nq][1]);
                const unsigned hi = pktrunc(oc[md][nq][2], oc[md][nq][3]);
                *reinterpret_cast<unsigned long long*>(
                    &os[(nq*16 + l15)*OSS + wv*32 + md*16 + l4*4]) =
                    ((unsigned long long)hi << 32) | lo;
            }
    }

    // ---- small prefetches only (st/pk/vfrag dead; no big arrays) ----
    float xres[6][4];
    #pragma unroll
    for (int nt = 0; nt < 6; ++nt)
        #pragma unroll
        for (int rg = 0; rg < 4; ++rg) {
            const int tok = wv*16 + l4*4 + rg;
            const int tokc = tok < WT ? tok : 48;   // clamp: pad rows read real data, discarded later
            xres[nt][rg] = x[((size_t)b * NTOK + (size_t)(xr*7 + tokc/7) * IMG + (yr*7 + tokc%7)) * DIM + nt*16 + l15];
        }
    float bo6[6], g6[6], be6[6];
    #pragma unroll
    for (int nt = 0; nt < 6; ++nt) {
        bo6[nt] = b_out[nt*16 + l15];
        g6[nt]  = ln2_g[nt*16 + l15];
        be6[nt] = ln2_b[nt*16 + l15];
    }
    __syncthreads();   // b4: os ready; all qk/hs history retired (h2 may clobber after)

    // ---- proj: os[64x128] @ Wout^T + b_out + xres -> yreg (weights inline) ----
    float yreg[6][4];
    {
        bf16x8 afr[4];
        #pragma unroll
        for (int kst = 0; kst < 4; ++kst)
            afr[kst] = *reinterpret_cast<const bf16x8*>(&os[(wv*16 + l15)*OSS + kst*32 + l4*8]);
        #pragma unroll
        for (int nt = 0; nt < 6; ++nt) {
            f32x4 acc = (f32x4){0.f,0.f,0.f,0.f};
            #pragma unroll
            for (int kst = 0; kst < 4; ++kst)
                acc = MFMA16(afr[kst], ldfrag(woutb, nt*4 + kst, lane), acc);
            #pragma unroll
            for (int rg = 0; rg < 4; ++rg)
                yreg[nt][rg] = acc[rg] + bo6[nt] + xres[nt][rg];
        }
    }

    // ---- LN2 in-register (row over 16 l15-lanes x 6 nt) ----
    float mu4[4], rs4[4];
    #pragma unroll
    for (int rg = 0; rg < 4; ++rg) {
        float s = 0.f, s2 = 0.f;
        #pragma unroll
        for (int nt = 0; nt < 6; ++nt) { const float v = yreg[nt][rg]; s += v; s2 += v*v; }
        s  += __shfl_xor(s, 1);  s  += __shfl_xor(s, 2);  s  += __shfl_xor(s, 4);  s  += __shfl_xor(s, 8);
        s2 += __shfl_xor(s2, 1); s2 += __shfl_xor(s2, 2); s2 += __shfl_xor(s2, 4); s2 += __shfl_xor(s2, 8);
        const float m = s * (1.f/96.f);
        mu4[rg] = m;
        rs4[rg] = rsqrtf(s2 * (1.f/96.f) - m*m + 1e-5f);
    }
    #pragma unroll
    for (int nt = 0; nt < 6; ++nt)
        #pragma unroll
        for (int rg = 0; rg < 4; ++rg)
            h2[(wv*16 + l4*4 + rg)*104 + nt*16 + l15] =
                f2bf((yreg[nt][rg] - mu4[rg]) * rs4[rg] * g6[nt] + be6[nt]);
    __syncthreads();   // b6: h2 ready; os fully consumed -> ts may overwrite

    // ---- FFN: GEMM1 halves (GELU -> ts) interleaved with GEMM2 k-partials ----
    f32x4 acc2[6];
    #pragma unroll
    for (int nt = 0; nt < 6; ++nt) acc2[nt] = (f32x4){0.f,0.f,0.f,0.f};

    #pragma unroll
    for (int al = 0; al < 2; ++al) {
        bf16x8 af[3][4];
        #pragma unroll
        for (int k3 = 0; k3 < 3; ++k3)
            #pragma unroll
            for (int mt = 0; mt < 4; ++mt)
                af[k3][mt] = *reinterpret_cast<const bf16x8*>(&h2[(mt*16 + l15)*104 + k3*32 + l4*8]);
        #pragma unroll
        for (int n3 = 0; n3 < 3; ++n3) {
            const int r1 = al*12 + wv*3 + n3;
            f32x4 a1[4];
            #pragma unroll
            for (int mt = 0; mt < 4; ++mt) a1[mt] = (f32x4){0.f,0.f,0.f,0.f};
            #pragma unroll
            for (int k3 = 0; k3 < 3; ++k3) {
                const bf16x8 bf = ldfrag(w1b, r1*3 + k3, lane);
                #pragma unroll
                for (int mt = 0; mt < 4; ++mt)
                    a1[mt] = MFMA16(af[k3][mt], bf, a1[mt]);
            }
            const float bb = b1[al*192 + wv*48 + n3*16 + l15];   // inline (L2-hot)
            #pragma unroll
            for (int mt = 0; mt < 4; ++mt)
                #pragma unroll
                for (int rg = 0; rg < 4; ++rg)
                    ts[(mt*16 + l4*4 + rg)*TSS + wv*48 + n3*16 + l15] = f2bf(gelu_f(a1[mt][rg] + bb));
        }
        __syncthreads();   // ts half ready
        bf16x8 at[6];
        #pragma unroll
        for (int kl = 0; kl < 6; ++kl)
            at[kl] = *reinterpret_cast<const bf16x8*>(&ts[(wv*16 + l15)*TSS + kl*32 + l4*8]);
        #pragma unroll
        for (int nt = 0; nt < 6; ++nt) {
            #pragma unroll
            for (int kl = 0; kl < 6; ++kl)
                acc2[nt] = MFMA16(at[kl], ldfrag(w2b, nt*12 + al*6 + kl, lane), acc2[nt]);
        }
        if (al == 0) __syncthreads();   // ts reads done before half-1 overwrites
    }

    // ---- final: y = gemm2 + b2 + yreg, single global write (b2 loaded inline) ----
    #pragma unroll
    for (int nt = 0; nt < 6; ++nt)
        #pragma unroll
        for (int rg = 0; rg < 4; ++rg) {
            const int tok = wv*16 + l4*4 + rg;
            if (tok < WT) {
                const size_t gi = ((size_t)b * NTOK + (size_t)(xr*7 + tok/7) * IMG + (yr*7 + tok%7)) * DIM + nt*16 + l15;
                y[gi] = acc2[nt][rg] + b2[nt*16 + l15] + yreg[nt][rg];
            }
        }
}

extern "C" void kernel_launch(void* const* d_in, const int* in_sizes, int n_in,
                              void* d_out, int out_size, void* d_ws, size_t ws_size,
                              hipStream_t stream) {
    const float* x     = (const float*)d_in[0];
    const float* w_qkv = (const float*)d_in[1];
    const float* w_out = (const float*)d_in[2];
    const float* b_out = (const float*)d_in[3];
    const float* rel_b = (const float*)d_in[4];
    const float* ln1_g = (const float*)d_in[5];
    const float* ln1_b = (const float*)d_in[6];
    const float* ln2_g = (const float*)d_in[7];
    const float* ln2_b = (const float*)d_in[8];
    const float* w1    = (const float*)d_in[9];
    const float* b1    = (const float*)d_in[10];
    const float* w2    = (const float*)d_in[11];
    const float* b2    = (const float*)d_in[12];
    float* y = (float*)d_out;
    char* ws = (char*)d_ws;

    prep_kernel<<<529, 256, 0, stream>>>(w_qkv, w_out, w1, w2, rel_b, ws);
    fused_kernel<<<NB * 32 * 32, 256, 0, stream>>>(x, ws, b_out, ln1_g, ln1_b,
                                                   ln2_g, ln2_b, b1, b2, y);
}

// Round 18
// 421.999 us; speedup vs baseline: 1.3079x; 1.3079x over previous
//
#include <hip/hip_runtime.h>
#include <math.h>

#define NB    8
#define IMG   224
#define NTOK  (IMG*IMG)          // 50176 per batch
#define DIM   96
#define INR   128
#define HIDN  384
#define WT    49
#define SCALE 0.17677669529663687f
#define QKS   72                 // qk LDS row stride (shorts): q cols 0..31, k cols 32..63
#define OSS   136                // os row stride (shorts)
#define TSS   200                // ts row stride (shorts)

typedef __attribute__((ext_vector_type(8))) short bf16x8;
typedef __attribute__((ext_vector_type(4))) float f32x4;
typedef __attribute__((ext_vector_type(4))) unsigned int u32x4;

#define MFMA16(a,b,c) __builtin_amdgcn_mfma_f32_16x16x32_bf16((a),(b),(c),0,0,0)

__device__ __forceinline__ short f2bf(float f) {
    unsigned u = __builtin_bit_cast(unsigned, f);
    u += 0x7fffu + ((u >> 16) & 1u);
    return (short)(u >> 16);
}

// truncating pack of two f32 -> packed bf16x2 (lo in low 16) — proven-safe bitwise form
__device__ __forceinline__ unsigned pktrunc(float lo, float hi) {
    return (__builtin_bit_cast(unsigned, hi) & 0xFFFF0000u) |
           (__builtin_bit_cast(unsigned, lo) >> 16);
}

// tanh-form GELU, constants folded: u = z*(1.5957691 + 0.07135482*z^2)
__device__ __forceinline__ float gelu_f(float z) {
    const float t = z * z;
    const float u = z * fmaf(0.07135482f, t, 1.5957691f);
    return z / (1.f + __expf(-u));
}

// fragment-major weight load: wave reads contiguous 1KB (tile*1024B + lane*16B)
__device__ __forceinline__ bf16x8 ldfrag(const short* base, int tile, int lane) {
    return *reinterpret_cast<const bf16x8*>(base + ((tile << 6) + lane) * 8);
}

// ---------- prep: weights -> bf16 in FRAGMENT-MAJOR layout; rel bias gathered ----------
__global__ void prep_kernel(const float* __restrict__ wqkv, const float* __restrict__ wout,
                            const float* __restrict__ w1,   const float* __restrict__ w2,
                            const float* __restrict__ rel_bias, char* __restrict__ ws)
{
    short* wqkvb = (short*)ws;                 // 36864 elems, tiles r<24, c<3
    short* woutb = (short*)(ws + 73728);       // 12288, tiles r<6, c<4
    short* w1b   = (short*)(ws + 98304);       // 36864, tiles r<24, c<3
    short* w2b   = (short*)(ws + 172032);      // 36864, tiles r<6, c<12
    float* biasp = (float*)(ws + 245760);      // [4][49][64] fp32, pre-scaled, key-padded
    const int idx = blockIdx.x * 256 + threadIdx.x;
    if (idx < 36864) {
        const int tile = idx >> 9, lane = (idx >> 3) & 63, j = idx & 7;
        const int r = tile / 3, c = tile % 3;
        wqkvb[idx] = f2bf(wqkv[(r*16 + (lane & 15))*96 + c*32 + (lane >> 4)*8 + j]);
    } else if (idx < 49152) {
        const int t = idx - 36864;
        const int tile = t >> 9, lane = (t >> 3) & 63, j = t & 7;
        const int r = tile >> 2, c = tile & 3;
        woutb[t] = f2bf(wout[(r*16 + (lane & 15))*128 + c*32 + (lane >> 4)*8 + j]);
    } else if (idx < 86016) {
        const int t = idx - 49152;
        const int tile = t >> 9, lane = (t >> 3) & 63, j = t & 7;
        const int r = tile / 3, c = tile % 3;
        w1b[t] = f2bf(w1[(r*16 + (lane & 15))*96 + c*32 + (lane >> 4)*8 + j]);
    } else if (idx < 122880) {
        const int t = idx - 86016;
        const int tile = t >> 9, lane = (t >> 3) & 63, j = t & 7;
        const int r = tile / 12, c = tile % 12;
        w2b[t] = f2bf(w2[(r*16 + (lane & 15))*384 + c*32 + (lane >> 4)*8 + j]);
    } else if (idx < 135424) {
        const int t = idx - 122880;
        const int h = t / 3136, r = t % 3136, q = r / 64, k = r % 64;
        float v = 0.f;
        if (k < 49) {
            const int rel = (q/7 - k/7 + 6) * 13 + (q%7 - k%7 + 6);
            v = rel_bias[rel * 4 + h] * SCALE;
        }
        biasp[t] = v;
    }
}

// ---------- fused kernel (R16/R13 structure + VALU/spill micro-cuts) ----------
// LDS pool (50176 B); hs and qk DISJOINT (no b2 barrier):
//   stage A: hs[64][104]            [0,13312)
//   stage B: qk[4][64][QKS]         [13312,50176)   wave-private q|k
//   stage C: os[64][OSS]            [13312,30720)   (aliases qk; gated by b3)
//   stage D: h2[64][104]            [0,13312)
//            ts[64][TSS]            [13312,38912)
// R18: LN1 packed u32 stores; 3-op GELU core; wofr prefetch HALVED ([4][3], rest inline)
// to cut the 148MB spill while keeping R14's proven prefetch benefit.
__global__ __launch_bounds__(256, 3) void fused_kernel(
    const float* __restrict__ x, const char* __restrict__ ws,
    const float* __restrict__ b_out, const float* __restrict__ ln1_g,
    const float* __restrict__ ln1_b, const float* __restrict__ ln2_g,
    const float* __restrict__ ln2_b, const float* __restrict__ b1,
    const float* __restrict__ b2, float* __restrict__ y)
{
    __shared__ __align__(16) char pool[50176];
    short* hs = (short*)pool;
    short* qk = (short*)(pool + 13312);
    short* os = (short*)(pool + 13312);
    short* h2 = (short*)pool;
    short* ts = (short*)(pool + 13312);

    const short* wqkvb = (const short*)ws;
    const short* woutb = (const short*)(ws + 73728);
    const short* w1b   = (const short*)(ws + 98304);
    const short* w2b   = (const short*)(ws + 172032);
    const float* biasp = (const float*)(ws + 245760);

    const int tid = threadIdx.x;
    const int wv  = tid >> 6;         // wave = head (attn) / M-tile (proj,FFN)
    const int lane = tid & 63;
    const int l15 = tid & 15;
    const int l4  = (tid & 63) >> 4;
    const int wid = blockIdx.x;
    const int b = wid >> 10, xr = (wid >> 5) & 31, yr = wid & 31;
    const int qkbase = wv * 64 * QKS;

    // ---- LN1: 4 threads per row, packed u32 stores (pktrunc, 4B-aligned) ----
    if (tid < 196) {
        const int i = tid >> 2, g = tid & 3;
        const float* xp = x + ((size_t)b * NTOK + (size_t)(xr*7 + i/7) * IMG + (yr*7 + i%7)) * DIM + g*24;
        float v[24]; float s = 0.f, s2 = 0.f;
        #pragma unroll
        for (int c = 0; c < 6; ++c) {
            const float4 t4 = *reinterpret_cast<const float4*>(xp + c*4);
            v[c*4+0]=t4.x; v[c*4+1]=t4.y; v[c*4+2]=t4.z; v[c*4+3]=t4.w;
            s  += t4.x + t4.y + t4.z + t4.w;
            s2 += t4.x*t4.x + t4.y*t4.y + t4.z*t4.z + t4.w*t4.w;
        }
        s  += __shfl_xor(s, 1);  s  += __shfl_xor(s, 2);
        s2 += __shfl_xor(s2, 1); s2 += __shfl_xor(s2, 2);
        const float mu = s * (1.f/96.f);
        const float rs = rsqrtf(s2 * (1.f/96.f) - mu*mu + 1e-5f);
        #pragma unroll
        for (int c = 0; c < 12; ++c) {
            const int d = g*24 + c*2;
            const float a0 = (v[c*2+0] - mu) * rs * ln1_g[d]   + ln1_b[d];
            const float a1 = (v[c*2+1] - mu) * rs * ln1_g[d+1] + ln1_b[d+1];
            *reinterpret_cast<unsigned*>(&hs[i*104 + d]) = pktrunc(a0, a1);
        }
    }
    for (int idx = tid; idx < 780; idx += 256)   // zero pad rows 49..63 (u32 writes)
        *reinterpret_cast<unsigned*>(&hs[49*104 + idx*2]) = 0;
    __syncthreads();   // b1: hs ready

    // ---- qkv pass A: q,k (acc[4][4] = 64 regs peak) ----
    {
        f32x4 acc[4][4];
        #pragma unroll
        for (int nt = 0; nt < 4; ++nt)
            #pragma unroll
            for (int mt = 0; mt < 4; ++mt)
                acc[nt][mt] = (f32x4){0.f,0.f,0.f,0.f};
        #pragma unroll
        for (int k3 = 0; k3 < 3; ++k3) {
            bf16x8 a4[4];
            #pragma unroll
            for (int mt = 0; mt < 4; ++mt)
                a4[mt] = *reinterpret_cast<const bf16x8*>(&hs[(mt*16 + l15)*104 + k3*32 + l4*8]);
            #pragma unroll
            for (int nt = 0; nt < 4; ++nt) {
                const int r = (nt < 2) ? wv*2 + nt : 8 + wv*2 + (nt-2);
                const bf16x8 bfr = ldfrag(wqkvb, r*3 + k3, lane);
                #pragma unroll
                for (int mt = 0; mt < 4; ++mt)
                    acc[nt][mt] = MFMA16(a4[mt], bfr, acc[nt][mt]);
            }
        }
        // q (cols 0..31), k (cols 32..63) -> wave-private LDS; qk disjoint from hs -> NO barrier
        #pragma unroll
        for (int nt = 0; nt < 4; ++nt) {
            const int col0 = nt*16;
            #pragma unroll
            for (int mt = 0; mt < 4; ++mt)
                #pragma unroll
                for (int rg = 0; rg < 4; ++rg)
                    qk[qkbase + (mt*16 + l4*4 + rg)*QKS + col0 + l15] = f2bf(acc[nt][mt][rg]);
        }
    }

    // ---- qkv pass B: v (acc[2][4] = 32 regs) -> vfrag registers ----
    u32x4 vfrag[2][2];   // V packed bf16, PV A-operand (regs only)
    {
        f32x4 accv[2][4];
        #pragma unroll
        for (int nv = 0; nv < 2; ++nv)
            #pragma unroll
            for (int mt = 0; mt < 4; ++mt)
                accv[nv][mt] = (f32x4){0.f,0.f,0.f,0.f};
        #pragma unroll
        for (int k3 = 0; k3 < 3; ++k3) {
            bf16x8 a4[4];
            #pragma unroll
            for (int mt = 0; mt < 4; ++mt)
                a4[mt] = *reinterpret_cast<const bf16x8*>(&hs[(mt*16 + l15)*104 + k3*32 + l4*8]);
            #pragma unroll
            for (int nv = 0; nv < 2; ++nv) {
                const bf16x8 bfr = ldfrag(wqkvb, (16 + wv*2 + nv)*3 + k3, lane);
                #pragma unroll
                for (int mt = 0; mt < 4; ++mt)
                    accv[nv][mt] = MFMA16(a4[mt], bfr, accv[nv][mt]);
            }
        }
        #pragma unroll
        for (int md = 0; md < 2; ++md)
            #pragma unroll
            for (int kst = 0; kst < 2; ++kst)
                vfrag[md][kst] = (u32x4){
                    pktrunc(accv[md][2*kst  ][0], accv[md][2*kst  ][1]),
                    pktrunc(accv[md][2*kst  ][2], accv[md][2*kst  ][3]),
                    pktrunc(accv[md][2*kst+1][0], accv[md][2*kst+1][1]),
                    pktrunc(accv[md][2*kst+1][2], accv[md][2*kst+1][3])};
    }
    // no barrier: qk store->read is same-wave (wave-private region)

    // ---- S^T = K @ Q^T (wave = head, wave-private LDS reads) ----
    f32x4 st[4][4];    // [mtKey][ntQuery]
    {
        bf16x8 kf[4], qf[4];
        #pragma unroll
        for (int mt = 0; mt < 4; ++mt)
            kf[mt] = *reinterpret_cast<const bf16x8*>(&qk[qkbase + (mt*16 + l15)*QKS + 32 + l4*8]);
        #pragma unroll
        for (int nt = 0; nt < 4; ++nt)
            qf[nt] = *reinterpret_cast<const bf16x8*>(&qk[qkbase + (nt*16 + l15)*QKS + l4*8]);
        #pragma unroll
        for (int mt = 0; mt < 4; ++mt)
            #pragma unroll
            for (int nt = 0; nt < 4; ++nt)
                st[mt][nt] = MFMA16(kf[mt], qf[nt], ((f32x4){0.f,0.f,0.f,0.f}));
    }
    __syncthreads();   // b3: all qk reads + hs reads done; os/h2 stores may clobber

    // ---- softmax over keys (in-lane 13 live + 2 shfl), pack P^T ----
    unsigned pk[4][4][2];   // [ntQuery][mtKey][pair]
    #pragma unroll
    for (int nq = 0; nq < 4; ++nq) {
        const int qc = (nq*16 + l15) < WT ? (nq*16 + l15) : 48;
        const float* bp = biasp + (wv*49 + qc)*64;
        float v[13];
        #pragma unroll
        for (int mk = 0; mk < 3; ++mk) {
            const float4 b4 = *reinterpret_cast<const float4*>(&bp[mk*16 + l4*4]);
            v[mk*4+0] = fmaf(st[mk][nq][0], SCALE, b4.x);
            v[mk*4+1] = fmaf(st[mk][nq][1], SCALE, b4.y);
            v[mk*4+2] = fmaf(st[mk][nq][2], SCALE, b4.z);
            v[mk*4+3] = fmaf(st[mk][nq][3], SCALE, b4.w);
        }
        v[12] = (l4 == 0) ? fmaf(st[3][nq][0], SCALE, bp[48]) : -1e30f;  // key 48
        float mx = v[0];
        #pragma unroll
        for (int t = 1; t < 13; ++t) mx = fmaxf(mx, v[t]);
        mx = fmaxf(mx, __shfl_xor(mx, 16));
        mx = fmaxf(mx, __shfl_xor(mx, 32));
        float sum = 0.f;
        #pragma unroll
        for (int t = 0; t < 13; ++t) { v[t] = __expf(v[t] - mx); sum += v[t]; }
        sum += __shfl_xor(sum, 16);
        sum += __shfl_xor(sum, 32);
        const float inv = 1.f / sum;
        #pragma unroll
        for (int mk = 0; mk < 3; ++mk) {
            pk[nq][mk][0] = pktrunc(v[mk*4+0]*inv, v[mk*4+1]*inv);
            pk[nq][mk][1] = pktrunc(v[mk*4+2]*inv, v[mk*4+3]*inv);
        }
        pk[nq][3][0] = pktrunc(v[12]*inv, 0.f);
        pk[nq][3][1] = 0u;
    }

    // ---- PV: o^T = V^T @ P^T — BOTH operands from registers ----
    {
        f32x4 oc[2][4];   // [mtDim][ntQuery]
        #pragma unroll
        for (int md = 0; md < 2; ++md)
            #pragma unroll
            for (int nq = 0; nq < 4; ++nq)
                oc[md][nq] = (f32x4){0.f,0.f,0.f,0.f};
        #pragma unroll
        for (int kst = 0; kst < 2; ++kst) {
            #pragma unroll
            for (int nq = 0; nq < 4; ++nq) {
                const bf16x8 bp8 = __builtin_bit_cast(bf16x8,
                    (u32x4){pk[nq][2*kst][0], pk[nq][2*kst][1], pk[nq][2*kst+1][0], pk[nq][2*kst+1][1]});
                #pragma unroll
                for (int md = 0; md < 2; ++md)
                    oc[md][nq] = MFMA16(__builtin_bit_cast(bf16x8, vfrag[md][kst]), bp8, oc[md][nq]);
            }
        }
        // os store (transpose back): os[query][inner]
        #pragma unroll
        for (int md = 0; md < 2; ++md)
            #pragma unroll
            for (int nq = 0; nq < 4; ++nq) {
                const unsigned lo = pktrunc(oc[md][nq][0], oc[md][nq][1]);
                const unsigned hi = pktrunc(oc[md][nq][2], oc[md][nq][3]);
                *reinterpret_cast<unsigned long long*>(
                    &os[(nq*16 + l15)*OSS + wv*32 + md*16 + l4*4]) =
                    ((unsigned long long)hi << 32) | lo;
            }
    }

    // ---- prefetches, placed AFTER PV so st/pk/vfrag are dead (no register peak) ----
    float xres[6][4];
    #pragma unroll
    for (int nt = 0; nt < 6; ++nt)
        #pragma unroll
        for (int rg = 0; rg < 4; ++rg) {
            const int tok = wv*16 + l4*4 + rg;
            const int tokc = tok < WT ? tok : 48;   // clamp: pad rows read real data, discarded later
            xres[nt][rg] = x[((size_t)b * NTOK + (size_t)(xr*7 + tokc/7) * IMG + (yr*7 + tokc%7)) * DIM + nt*16 + l15];
        }
    bf16x8 wofr[4][3];   // HALF prefetch (48 regs): nt 0..2; nt 3..5 loaded inline in proj
    float bo6[6], g6[6], be6[6], b26[6], b1p[6];
    #pragma unroll
    for (int nt = 0; nt < 6; ++nt) {
        bo6[nt] = b_out[nt*16 + l15];
        g6[nt]  = ln2_g[nt*16 + l15];
        be6[nt] = ln2_b[nt*16 + l15];
        b26[nt] = b2[nt*16 + l15];
    }
    #pragma unroll
    for (int nt = 0; nt < 3; ++nt)
        #pragma unroll
        for (int kst = 0; kst < 4; ++kst)
            wofr[kst][nt] = ldfrag(woutb, nt*4 + kst, lane);
    #pragma unroll
    for (int al = 0; al < 2; ++al)
        #pragma unroll
        for (int n3 = 0; n3 < 3; ++n3)
            b1p[al*3 + n3] = b1[al*192 + wv*48 + n3*16 + l15];
    __syncthreads();   // b4: os ready

    // ---- proj: os[64x128] @ Wout^T + b_out + xres -> yreg (no b5: h2 disjoint from os) ----
    float yreg[6][4];
    {
        bf16x8 afr[4];
        #pragma unroll
        for (int kst = 0; kst < 4; ++kst)
            afr[kst] = *reinterpret_cast<const bf16x8*>(&os[(wv*16 + l15)*OSS + kst*32 + l4*8]);
        #pragma unroll
        for (int nt = 0; nt < 6; ++nt) {
            f32x4 acc = (f32x4){0.f,0.f,0.f,0.f};
            #pragma unroll
            for (int kst = 0; kst < 4; ++kst) {
                const bf16x8 wfr = (nt < 3) ? wofr[kst][nt] : ldfrag(woutb, nt*4 + kst, lane);
                acc = MFMA16(afr[kst], wfr, acc);
            }
            #pragma unroll
            for (int rg = 0; rg < 4; ++rg)
                yreg[nt][rg] = acc[rg] + bo6[nt] + xres[nt][rg];
        }
    }

    // ---- LN2 in-register (row over 16 l15-lanes x 6 nt) ----
    float mu4[4], rs4[4];
    #pragma unroll
    for (int rg = 0; rg < 4; ++rg) {
        float s = 0.f, s2 = 0.f;
        #pragma unroll
        for (int nt = 0; nt < 6; ++nt) { const float v = yreg[nt][rg]; s += v; s2 += v*v; }
        s  += __shfl_xor(s, 1);  s  += __shfl_xor(s, 2);  s  += __shfl_xor(s, 4);  s  += __shfl_xor(s, 8);
        s2 += __shfl_xor(s2, 1); s2 += __shfl_xor(s2, 2); s2 += __shfl_xor(s2, 4); s2 += __shfl_xor(s2, 8);
        const float m = s * (1.f/96.f);
        mu4[rg] = m;
        rs4[rg] = rsqrtf(s2 * (1.f/96.f) - m*m + 1e-5f);
    }
    #pragma unroll
    for (int nt = 0; nt < 6; ++nt)
        #pragma unroll
        for (int rg = 0; rg < 4; ++rg)
            h2[(wv*16 + l4*4 + rg)*104 + nt*16 + l15] =
                f2bf((yreg[nt][rg] - mu4[rg]) * rs4[rg] * g6[nt] + be6[nt]);
    __syncthreads();   // b6: h2 ready (os fully consumed; ts may overwrite it after this)

    // ---- FFN: GEMM1 halves (GELU -> ts) interleaved with GEMM2 k-partials ----
    f32x4 acc2[6];
    #pragma unroll
    for (int nt = 0; nt < 6; ++nt) acc2[nt] = (f32x4){0.f,0.f,0.f,0.f};

    #pragma unroll
    for (int al = 0; al < 2; ++al) {
        bf16x8 af[3][4];
        #pragma unroll
        for (int k3 = 0; k3 < 3; ++k3)
            #pragma unroll
            for (int mt = 0; mt < 4; ++mt)
                af[k3][mt] = *reinterpret_cast<const bf16x8*>(&h2[(mt*16 + l15)*104 + k3*32 + l4*8]);
        #pragma unroll
        for (int n3 = 0; n3 < 3; ++n3) {
            const int r1 = al*12 + wv*3 + n3;
            f32x4 a1[4];
            #pragma unroll
            for (int mt = 0; mt < 4; ++mt) a1[mt] = (f32x4){0.f,0.f,0.f,0.f};
            #pragma unroll
            for (int k3 = 0; k3 < 3; ++k3) {
                const bf16x8 bf = ldfrag(w1b, r1*3 + k3, lane);
                #pragma unroll
                for (int mt = 0; mt < 4; ++mt)
                    a1[mt] = MFMA16(af[k3][mt], bf, a1[mt]);
            }
            const float bb = b1p[al*3 + n3];
            #pragma unroll
            for (int mt = 0; mt < 4; ++mt)
                #pragma unroll
                for (int rg = 0; rg < 4; ++rg)
                    ts[(mt*16 + l4*4 + rg)*TSS + wv*48 + n3*16 + l15] = f2bf(gelu_f(a1[mt][rg] + bb));
        }
        __syncthreads();   // ts half ready
        bf16x8 at[6];
        #pragma unroll
        for (int kl = 0; kl < 6; ++kl)
            at[kl] = *reinterpret_cast<const bf16x8*>(&ts[(wv*16 + l15)*TSS + kl*32 + l4*8]);
        #pragma unroll
        for (int nt = 0; nt < 6; ++nt) {
            #pragma unroll
            for (int kl = 0; kl < 6; ++kl)
                acc2[nt] = MFMA16(at[kl], ldfrag(w2b, nt*12 + al*6 + kl, lane), acc2[nt]);
        }
        if (al == 0) __syncthreads();   // ts reads done before half-1 overwrites
    }

    // ---- final: y = gemm2 + b2 + yreg, single global write ----
    #pragma unroll
    for (int nt = 0; nt < 6; ++nt)
        #pragma unroll
        for (int rg = 0; rg < 4; ++rg) {
            const int tok = wv*16 + l4*4 + rg;
            if (tok < WT) {
                const size_t gi = ((size_t)b * NTOK + (size_t)(xr*7 + tok/7) * IMG + (yr*7 + tok%7)) * DIM + nt*16 + l15;
                y[gi] = acc2[nt][rg] + b26[nt] + yreg[nt][rg];
            }
        }
}

extern "C" void kernel_launch(void* const* d_in, const int* in_sizes, int n_in,
                              void* d_out, int out_size, void* d_ws, size_t ws_size,
                              hipStream_t stream) {
    const float* x     = (const float*)d_in[0];
    const float* w_qkv = (const float*)d_in[1];
    const float* w_out = (const float*)d_in[2];
    const float* b_out = (const float*)d_in[3];
    const float* rel_b = (const float*)d_in[4];
    const float* ln1_g = (const float*)d_in[5];
    const float* ln1_b = (const float*)d_in[6];
    const float* ln2_g = (const float*)d_in[7];
    const float* ln2_b = (const float*)d_in[8];
    const float* w1    = (const float*)d_in[9];
    const float* b1    = (const float*)d_in[10];
    const float* w2    = (const float*)d_in[11];
    const float* b2    = (const float*)d_in[12];
    float* y = (float*)d_out;
    char* ws = (char*)d_ws;

    prep_kernel<<<529, 256, 0, stream>>>(w_qkv, w_out, w1, w2, rel_b, ws);
    fused_kernel<<<NB * 32 * 32, 256, 0, stream>>>(x, ws, b_out, ln1_g, ln1_b,
                                                   ln2_g, ln2_b, b1, b2, y);
}

// Round 19
// 351.960 us; speedup vs baseline: 1.5682x; 1.1990x over previous
//
#include <hip/hip_runtime.h>
#include <math.h>

#define NB    8
#define IMG   224
#define NTOK  (IMG*IMG)          // 50176 per batch
#define DIM   96
#define INR   128
#define HIDN  384
#define WT    49
#define SCALE 0.17677669529663687f
#define QKS   72                 // qk LDS row stride (shorts): q cols 0..31, k cols 32..63
#define OSS   136                // os row stride (shorts)
#define TSS   200                // ts row stride (shorts)

typedef __attribute__((ext_vector_type(8))) short bf16x8;
typedef __attribute__((ext_vector_type(4))) float f32x4;
typedef __attribute__((ext_vector_type(4))) unsigned int u32x4;

#define MFMA16(a,b,c) __builtin_amdgcn_mfma_f32_16x16x32_bf16((a),(b),(c),0,0,0)

__device__ __forceinline__ short f2bf(float f) {
    unsigned u = __builtin_bit_cast(unsigned, f);
    u += 0x7fffu + ((u >> 16) & 1u);
    return (short)(u >> 16);
}

// truncating pack of two f32 -> packed bf16x2 (lo in low 16)
__device__ __forceinline__ unsigned pktrunc(float lo, float hi) {
    return (__builtin_bit_cast(unsigned, hi) & 0xFFFF0000u) |
           (__builtin_bit_cast(unsigned, lo) >> 16);
}

// tanh-form GELU, constants folded
__device__ __forceinline__ float gelu_f(float z) {
    const float t = z * z;
    const float u = z * fmaf(0.07135482f, t, 1.5957691f);
    return z / (1.f + __expf(-u));
}

// fragment-major weight load: wave reads contiguous 1KB (tile*1024B + lane*16B)
__device__ __forceinline__ bf16x8 ldfrag(const short* base, int tile, int lane) {
    return *reinterpret_cast<const bf16x8*>(base + ((tile << 6) + lane) * 8);
}

// ---------- prep: weights -> bf16 in FRAGMENT-MAJOR layout; rel bias gathered ----------
__global__ void prep_kernel(const float* __restrict__ wqkv, const float* __restrict__ wout,
                            const float* __restrict__ w1,   const float* __restrict__ w2,
                            const float* __restrict__ rel_bias, char* __restrict__ ws)
{
    short* wqkvb = (short*)ws;                 // 36864 elems, tiles r<24, c<3
    short* woutb = (short*)(ws + 73728);       // 12288, tiles r<6, c<4
    short* w1b   = (short*)(ws + 98304);       // 36864, tiles r<24, c<3
    short* w2b   = (short*)(ws + 172032);      // 36864, tiles r<6, c<12
    float* biasp = (float*)(ws + 245760);      // [4][49][64] fp32, pre-scaled, key-padded
    const int idx = blockIdx.x * 256 + threadIdx.x;
    if (idx < 36864) {
        const int tile = idx >> 9, lane = (idx >> 3) & 63, j = idx & 7;
        const int r = tile / 3, c = tile % 3;
        wqkvb[idx] = f2bf(wqkv[(r*16 + (lane & 15))*96 + c*32 + (lane >> 4)*8 + j]);
    } else if (idx < 49152) {
        const int t = idx - 36864;
        const int tile = t >> 9, lane = (t >> 3) & 63, j = t & 7;
        const int r = tile >> 2, c = tile & 3;
        woutb[t] = f2bf(wout[(r*16 + (lane & 15))*128 + c*32 + (lane >> 4)*8 + j]);
    } else if (idx < 86016) {
        const int t = idx - 49152;
        const int tile = t >> 9, lane = (t >> 3) & 63, j = t & 7;
        const int r = tile / 3, c = tile % 3;
        w1b[t] = f2bf(w1[(r*16 + (lane & 15))*96 + c*32 + (lane >> 4)*8 + j]);
    } else if (idx < 122880) {
        const int t = idx - 86016;
        const int tile = t >> 9, lane = (t >> 3) & 63, j = t & 7;
        const int r = tile / 12, c = tile % 12;
        w2b[t] = f2bf(w2[(r*16 + (lane & 15))*384 + c*32 + (lane >> 4)*8 + j]);
    } else if (idx < 135424) {
        const int t = idx - 122880;
        const int h = t / 3136, r = t % 3136, q = r / 64, k = r % 64;
        float v = 0.f;
        if (k < 49) {
            const int rel = (q/7 - k/7 + 6) * 13 + (q%7 - k%7 + 6);
            v = rel_bias[rel * 4 + h] * SCALE;
        }
        biasp[t] = v;
    }
}

// ---------- fused kernel (R18 base + row-partitioned FFN -> zero FFN barriers) ----------
// LDS pool (50176 B); hs and qk DISJOINT (no b2 barrier):
//   stage A: hs[64][104]            [0,13312)
//   stage B: qk[4][64][QKS]         [13312,50176)   wave-private q|k
//   stage C: os[64][OSS]            [13312,30720)   (aliases qk; gated by b3)
//   stage D: h2[64][104]            [0,13312)
//            ts[64][TSS]            [13312,38912)   rows wave-private in FFN
// R19: FFN GEMM1 row-partitioned (wave owns rows wv*16..+15, all cols) -> GEMM1/GEMM2
// ts dependency is same-wave -> BOTH FFN barriers deleted (4 barriers total). FFN regs
// collapse (af[3], single a1) -> residual spill should vanish.
__global__ __launch_bounds__(256, 3) void fused_kernel(
    const float* __restrict__ x, const char* __restrict__ ws,
    const float* __restrict__ b_out, const float* __restrict__ ln1_g,
    const float* __restrict__ ln1_b, const float* __restrict__ ln2_g,
    const float* __restrict__ ln2_b, const float* __restrict__ b1,
    const float* __restrict__ b2, float* __restrict__ y)
{
    __shared__ __align__(16) char pool[50176];
    short* hs = (short*)pool;
    short* qk = (short*)(pool + 13312);
    short* os = (short*)(pool + 13312);
    short* h2 = (short*)pool;
    short* ts = (short*)(pool + 13312);

    const short* wqkvb = (const short*)ws;
    const short* woutb = (const short*)(ws + 73728);
    const short* w1b   = (const short*)(ws + 98304);
    const short* w2b   = (const short*)(ws + 172032);
    const float* biasp = (const float*)(ws + 245760);

    const int tid = threadIdx.x;
    const int wv  = tid >> 6;         // wave = head (attn) / M-tile (proj,FFN)
    const int lane = tid & 63;
    const int l15 = tid & 15;
    const int l4  = (tid & 63) >> 4;
    const int wid = blockIdx.x;
    const int b = wid >> 10, xr = (wid >> 5) & 31, yr = wid & 31;
    const int qkbase = wv * 64 * QKS;

    // ---- LN1: 4 threads per row, packed u32 stores ----
    if (tid < 196) {
        const int i = tid >> 2, g = tid & 3;
        const float* xp = x + ((size_t)b * NTOK + (size_t)(xr*7 + i/7) * IMG + (yr*7 + i%7)) * DIM + g*24;
        float v[24]; float s = 0.f, s2 = 0.f;
        #pragma unroll
        for (int c = 0; c < 6; ++c) {
            const float4 t4 = *reinterpret_cast<const float4*>(xp + c*4);
            v[c*4+0]=t4.x; v[c*4+1]=t4.y; v[c*4+2]=t4.z; v[c*4+3]=t4.w;
            s  += t4.x + t4.y + t4.z + t4.w;
            s2 += t4.x*t4.x + t4.y*t4.y + t4.z*t4.z + t4.w*t4.w;
        }
        s  += __shfl_xor(s, 1);  s  += __shfl_xor(s, 2);
        s2 += __shfl_xor(s2, 1); s2 += __shfl_xor(s2, 2);
        const float mu = s * (1.f/96.f);
        const float rs = rsqrtf(s2 * (1.f/96.f) - mu*mu + 1e-5f);
        #pragma unroll
        for (int c = 0; c < 12; ++c) {
            const int d = g*24 + c*2;
            const float a0 = (v[c*2+0] - mu) * rs * ln1_g[d]   + ln1_b[d];
            const float a1 = (v[c*2+1] - mu) * rs * ln1_g[d+1] + ln1_b[d+1];
            *reinterpret_cast<unsigned*>(&hs[i*104 + d]) = pktrunc(a0, a1);
        }
    }
    for (int idx = tid; idx < 780; idx += 256)
        *reinterpret_cast<unsigned*>(&hs[49*104 + idx*2]) = 0;
    __syncthreads();   // b1: hs ready

    // ---- qkv pass A: q,k (acc[4][4] = 64 regs peak) ----
    {
        f32x4 acc[4][4];
        #pragma unroll
        for (int nt = 0; nt < 4; ++nt)
            #pragma unroll
            for (int mt = 0; mt < 4; ++mt)
                acc[nt][mt] = (f32x4){0.f,0.f,0.f,0.f};
        #pragma unroll
        for (int k3 = 0; k3 < 3; ++k3) {
            bf16x8 a4[4];
            #pragma unroll
            for (int mt = 0; mt < 4; ++mt)
                a4[mt] = *reinterpret_cast<const bf16x8*>(&hs[(mt*16 + l15)*104 + k3*32 + l4*8]);
            #pragma unroll
            for (int nt = 0; nt < 4; ++nt) {
                const int r = (nt < 2) ? wv*2 + nt : 8 + wv*2 + (nt-2);
                const bf16x8 bfr = ldfrag(wqkvb, r*3 + k3, lane);
                #pragma unroll
                for (int mt = 0; mt < 4; ++mt)
                    acc[nt][mt] = MFMA16(a4[mt], bfr, acc[nt][mt]);
            }
        }
        // q (cols 0..31), k (cols 32..63) -> wave-private LDS; qk disjoint from hs -> NO barrier
        #pragma unroll
        for (int nt = 0; nt < 4; ++nt) {
            const int col0 = nt*16;
            #pragma unroll
            for (int mt = 0; mt < 4; ++mt)
                #pragma unroll
                for (int rg = 0; rg < 4; ++rg)
                    qk[qkbase + (mt*16 + l4*4 + rg)*QKS + col0 + l15] = f2bf(acc[nt][mt][rg]);
        }
    }

    // ---- qkv pass B: v (acc[2][4] = 32 regs) -> vfrag registers ----
    u32x4 vfrag[2][2];
    {
        f32x4 accv[2][4];
        #pragma unroll
        for (int nv = 0; nv < 2; ++nv)
            #pragma unroll
            for (int mt = 0; mt < 4; ++mt)
                accv[nv][mt] = (f32x4){0.f,0.f,0.f,0.f};
        #pragma unroll
        for (int k3 = 0; k3 < 3; ++k3) {
            bf16x8 a4[4];
            #pragma unroll
            for (int mt = 0; mt < 4; ++mt)
                a4[mt] = *reinterpret_cast<const bf16x8*>(&hs[(mt*16 + l15)*104 + k3*32 + l4*8]);
            #pragma unroll
            for (int nv = 0; nv < 2; ++nv) {
                const bf16x8 bfr = ldfrag(wqkvb, (16 + wv*2 + nv)*3 + k3, lane);
                #pragma unroll
                for (int mt = 0; mt < 4; ++mt)
                    accv[nv][mt] = MFMA16(a4[mt], bfr, accv[nv][mt]);
            }
        }
        #pragma unroll
        for (int md = 0; md < 2; ++md)
            #pragma unroll
            for (int kst = 0; kst < 2; ++kst)
                vfrag[md][kst] = (u32x4){
                    pktrunc(accv[md][2*kst  ][0], accv[md][2*kst  ][1]),
                    pktrunc(accv[md][2*kst  ][2], accv[md][2*kst  ][3]),
                    pktrunc(accv[md][2*kst+1][0], accv[md][2*kst+1][1]),
                    pktrunc(accv[md][2*kst+1][2], accv[md][2*kst+1][3])};
    }
    // no barrier: qk store->read is same-wave (wave-private region)

    // ---- S^T = K @ Q^T (wave = head, wave-private LDS reads) ----
    f32x4 st[4][4];
    {
        bf16x8 kf[4], qf[4];
        #pragma unroll
        for (int mt = 0; mt < 4; ++mt)
            kf[mt] = *reinterpret_cast<const bf16x8*>(&qk[qkbase + (mt*16 + l15)*QKS + 32 + l4*8]);
        #pragma unroll
        for (int nt = 0; nt < 4; ++nt)
            qf[nt] = *reinterpret_cast<const bf16x8*>(&qk[qkbase + (nt*16 + l15)*QKS + l4*8]);
        #pragma unroll
        for (int mt = 0; mt < 4; ++mt)
            #pragma unroll
            for (int nt = 0; nt < 4; ++nt)
                st[mt][nt] = MFMA16(kf[mt], qf[nt], ((f32x4){0.f,0.f,0.f,0.f}));
    }
    __syncthreads();   // b3: all qk reads + hs reads done; os/h2 stores may clobber

    // ---- softmax over keys (in-lane 13 live + 2 shfl), pack P^T ----
    unsigned pk[4][4][2];
    #pragma unroll
    for (int nq = 0; nq < 4; ++nq) {
        const int qc = (nq*16 + l15) < WT ? (nq*16 + l15) : 48;
        const float* bp = biasp + (wv*49 + qc)*64;
        float v[13];
        #pragma unroll
        for (int mk = 0; mk < 3; ++mk) {
            const float4 b4 = *reinterpret_cast<const float4*>(&bp[mk*16 + l4*4]);
            v[mk*4+0] = fmaf(st[mk][nq][0], SCALE, b4.x);
            v[mk*4+1] = fmaf(st[mk][nq][1], SCALE, b4.y);
            v[mk*4+2] = fmaf(st[mk][nq][2], SCALE, b4.z);
            v[mk*4+3] = fmaf(st[mk][nq][3], SCALE, b4.w);
        }
        v[12] = (l4 == 0) ? fmaf(st[3][nq][0], SCALE, bp[48]) : -1e30f;  // key 48
        float mx = v[0];
        #pragma unroll
        for (int t = 1; t < 13; ++t) mx = fmaxf(mx, v[t]);
        mx = fmaxf(mx, __shfl_xor(mx, 16));
        mx = fmaxf(mx, __shfl_xor(mx, 32));
        float sum = 0.f;
        #pragma unroll
        for (int t = 0; t < 13; ++t) { v[t] = __expf(v[t] - mx); sum += v[t]; }
        sum += __shfl_xor(sum, 16);
        sum += __shfl_xor(sum, 32);
        const float inv = 1.f / sum;
        #pragma unroll
        for (int mk = 0; mk < 3; ++mk) {
            pk[nq][mk][0] = pktrunc(v[mk*4+0]*inv, v[mk*4+1]*inv);
            pk[nq][mk][1] = pktrunc(v[mk*4+2]*inv, v[mk*4+3]*inv);
        }
        pk[nq][3][0] = pktrunc(v[12]*inv, 0.f);
        pk[nq][3][1] = 0u;
    }

    // ---- PV: o^T = V^T @ P^T — BOTH operands from registers ----
    {
        f32x4 oc[2][4];
        #pragma unroll
        for (int md = 0; md < 2; ++md)
            #pragma unroll
            for (int nq = 0; nq < 4; ++nq)
                oc[md][nq] = (f32x4){0.f,0.f,0.f,0.f};
        #pragma unroll
        for (int kst = 0; kst < 2; ++kst) {
            #pragma unroll
            for (int nq = 0; nq < 4; ++nq) {
                const bf16x8 bp8 = __builtin_bit_cast(bf16x8,
                    (u32x4){pk[nq][2*kst][0], pk[nq][2*kst][1], pk[nq][2*kst+1][0], pk[nq][2*kst+1][1]});
                #pragma unroll
                for (int md = 0; md < 2; ++md)
                    oc[md][nq] = MFMA16(__builtin_bit_cast(bf16x8, vfrag[md][kst]), bp8, oc[md][nq]);
            }
        }
        #pragma unroll
        for (int md = 0; md < 2; ++md)
            #pragma unroll
            for (int nq = 0; nq < 4; ++nq) {
                const unsigned lo = pktrunc(oc[md][nq][0], oc[md][nq][1]);
                const unsigned hi = pktrunc(oc[md][nq][2], oc[md][nq][3]);
                *reinterpret_cast<unsigned long long*>(
                    &os[(nq*16 + l15)*OSS + wv*32 + md*16 + l4*4]) =
                    ((unsigned long long)hi << 32) | lo;
            }
    }

    // ---- prefetches (st/pk/vfrag dead -> no register peak) ----
    float xres[6][4];
    #pragma unroll
    for (int nt = 0; nt < 6; ++nt)
        #pragma unroll
        for (int rg = 0; rg < 4; ++rg) {
            const int tok = wv*16 + l4*4 + rg;
            const int tokc = tok < WT ? tok : 48;
            xres[nt][rg] = x[((size_t)b * NTOK + (size_t)(xr*7 + tokc/7) * IMG + (yr*7 + tokc%7)) * DIM + nt*16 + l15];
        }
    bf16x8 wofr[4][3];   // half prefetch: nt 0..2; nt 3..5 inline
    float bo6[6], g6[6], be6[6], b26[6];
    #pragma unroll
    for (int nt = 0; nt < 6; ++nt) {
        bo6[nt] = b_out[nt*16 + l15];
        g6[nt]  = ln2_g[nt*16 + l15];
        be6[nt] = ln2_b[nt*16 + l15];
        b26[nt] = b2[nt*16 + l15];
    }
    #pragma unroll
    for (int nt = 0; nt < 3; ++nt)
        #pragma unroll
        for (int kst = 0; kst < 4; ++kst)
            wofr[kst][nt] = ldfrag(woutb, nt*4 + kst, lane);
    __syncthreads();   // b4: os ready

    // ---- proj: os[64x128] @ Wout^T + b_out + xres -> yreg ----
    float yreg[6][4];
    {
        bf16x8 afr[4];
        #pragma unroll
        for (int kst = 0; kst < 4; ++kst)
            afr[kst] = *reinterpret_cast<const bf16x8*>(&os[(wv*16 + l15)*OSS + kst*32 + l4*8]);
        #pragma unroll
        for (int nt = 0; nt < 6; ++nt) {
            f32x4 acc = (f32x4){0.f,0.f,0.f,0.f};
            #pragma unroll
            for (int kst = 0; kst < 4; ++kst) {
                const bf16x8 wfr = (nt < 3) ? wofr[kst][nt] : ldfrag(woutb, nt*4 + kst, lane);
                acc = MFMA16(afr[kst], wfr, acc);
            }
            #pragma unroll
            for (int rg = 0; rg < 4; ++rg)
                yreg[nt][rg] = acc[rg] + bo6[nt] + xres[nt][rg];
        }
    }

    // ---- LN2 in-register (row over 16 l15-lanes x 6 nt) ----
    float mu4[4], rs4[4];
    #pragma unroll
    for (int rg = 0; rg < 4; ++rg) {
        float s = 0.f, s2 = 0.f;
        #pragma unroll
        for (int nt = 0; nt < 6; ++nt) { const float v = yreg[nt][rg]; s += v; s2 += v*v; }
        s  += __shfl_xor(s, 1);  s  += __shfl_xor(s, 2);  s  += __shfl_xor(s, 4);  s  += __shfl_xor(s, 8);
        s2 += __shfl_xor(s2, 1); s2 += __shfl_xor(s2, 2); s2 += __shfl_xor(s2, 4); s2 += __shfl_xor(s2, 8);
        const float m = s * (1.f/96.f);
        mu4[rg] = m;
        rs4[rg] = rsqrtf(s2 * (1.f/96.f) - m*m + 1e-5f);
    }
    #pragma unroll
    for (int nt = 0; nt < 6; ++nt)
        #pragma unroll
        for (int rg = 0; rg < 4; ++rg)
            h2[(wv*16 + l4*4 + rg)*104 + nt*16 + l15] =
                f2bf((yreg[nt][rg] - mu4[rg]) * rs4[rg] * g6[nt] + be6[nt]);
    __syncthreads();   // b6: h2 ready; os fully consumed -> ts may overwrite

    // ---- FFN: ROW-PARTITIONED. Wave owns token rows wv*16..+15 end-to-end.
    //      GEMM1 own-rows x all cols -> ts own rows (wave-private) -> GEMM2 own rows.
    //      ZERO barriers (same-wave LDS ordering; al=1 overwrites only own rows). ----
    f32x4 acc2[6];
    #pragma unroll
    for (int nt = 0; nt < 6; ++nt) acc2[nt] = (f32x4){0.f,0.f,0.f,0.f};

    #pragma unroll
    for (int al = 0; al < 2; ++al) {
        bf16x8 af[3];
        #pragma unroll
        for (int k3 = 0; k3 < 3; ++k3)
            af[k3] = *reinterpret_cast<const bf16x8*>(&h2[(wv*16 + l15)*104 + k3*32 + l4*8]);
        #pragma unroll
        for (int n12 = 0; n12 < 12; ++n12) {
            f32x4 a1 = (f32x4){0.f,0.f,0.f,0.f};
            #pragma unroll
            for (int k3 = 0; k3 < 3; ++k3)
                a1 = MFMA16(af[k3], ldfrag(w1b, (al*12 + n12)*3 + k3, lane), a1);
            const float bb = b1[al*192 + n12*16 + l15];   // inline, L2-hot
            #pragma unroll
            for (int rg = 0; rg < 4; ++rg)
                ts[(wv*16 + l4*4 + rg)*TSS + n12*16 + l15] = f2bf(gelu_f(a1[rg] + bb));
        }
        // no barrier: ts rows wave-private; store->read same wave
        bf16x8 at[6];
        #pragma unroll
        for (int kl = 0; kl < 6; ++kl)
            at[kl] = *reinterpret_cast<const bf16x8*>(&ts[(wv*16 + l15)*TSS + kl*32 + l4*8]);
        #pragma unroll
        for (int nt = 0; nt < 6; ++nt) {
            #pragma unroll
            for (int kl = 0; kl < 6; ++kl)
                acc2[nt] = MFMA16(at[kl], ldfrag(w2b, nt*12 + al*6 + kl, lane), acc2[nt]);
        }
        // no barrier between halves: wave overwrites only its OWN ts rows
    }

    // ---- final: y = gemm2 + b2 + yreg, single global write ----
    #pragma unroll
    for (int nt = 0; nt < 6; ++nt)
        #pragma unroll
        for (int rg = 0; rg < 4; ++rg) {
            const int tok = wv*16 + l4*4 + rg;
            if (tok < WT) {
                const size_t gi = ((size_t)b * NTOK + (size_t)(xr*7 + tok/7) * IMG + (yr*7 + tok%7)) * DIM + nt*16 + l15;
                y[gi] = acc2[nt][rg] + b26[nt] + yreg[nt][rg];
            }
        }
}

extern "C" void kernel_launch(void* const* d_in, const int* in_sizes, int n_in,
                              void* d_out, int out_size, void* d_ws, size_t ws_size,
                              hipStream_t stream) {
    const float* x     = (const float*)d_in[0];
    const float* w_qkv = (const float*)d_in[1];
    const float* w_out = (const float*)d_in[2];
    const float* b_out = (const float*)d_in[3];
    const float* rel_b = (const float*)d_in[4];
    const float* ln1_g = (const float*)d_in[5];
    const float* ln1_b = (const float*)d_in[6];
    const float* ln2_g = (const float*)d_in[7];
    const float* ln2_b = (const float*)d_in[8];
    const float* w1    = (const float*)d_in[9];
    const float* b1    = (const float*)d_in[10];
    const float* w2    = (const float*)d_in[11];
    const float* b2    = (const float*)d_in[12];
    float* y = (float*)d_out;
    char* ws = (char*)d_ws;

    prep_kernel<<<529, 256, 0, stream>>>(w_qkv, w_out, w1, w2, rel_b, ws);
    fused_kernel<<<NB * 32 * 32, 256, 0, stream>>>(x, ws, b_out, ln1_g, ln1_b,
                                                   ln2_g, ln2_b, b1, b2, y);
}

// Round 21
// 349.556 us; speedup vs baseline: 1.5790x; 1.0069x over previous
//
#include <hip/hip_runtime.h>
#include <math.h>

#define NB    8
#define IMG   224
#define NTOK  (IMG*IMG)          // 50176 per batch
#define DIM   96
#define INR   128
#define HIDN  384
#define WT    49
#define SCALE 0.17677669529663687f
#define LOG2E 1.4426950408889634f
#define SCL2  (SCALE * LOG2E)    // QK^T scale folded with log2(e) for exp2-domain softmax
#define QKS   72                 // qk LDS row stride (shorts): q cols 0..31, k cols 32..63
#define OSS   136                // os row stride (shorts)
#define TSS   200                // ts row stride (shorts)

typedef __attribute__((ext_vector_type(8))) short bf16x8;
typedef __attribute__((ext_vector_type(4))) float f32x4;
typedef __attribute__((ext_vector_type(4))) unsigned int u32x4;

#define MFMA16(a,b,c) __builtin_amdgcn_mfma_f32_16x16x32_bf16((a),(b),(c),0,0,0)

__device__ __forceinline__ short f2bf(float f) {       // round-to-nearest (prep only)
    unsigned u = __builtin_bit_cast(unsigned, f);
    u += 0x7fffu + ((u >> 16) & 1u);
    return (short)(u >> 16);
}

// truncating conversions (1 VALU op); error <= 2^-8 relative, proven in-budget since R6
__device__ __forceinline__ short bftrunc(float f) {
    return (short)(__builtin_bit_cast(unsigned, f) >> 16);
}
__device__ __forceinline__ unsigned pktrunc(float lo, float hi) {
    return (__builtin_bit_cast(unsigned, hi) & 0xFFFF0000u) |
           (__builtin_bit_cast(unsigned, lo) >> 16);
}

// tanh-form GELU, constants folded
__device__ __forceinline__ float gelu_f(float z) {
    const float t = z * z;
    const float u = z * fmaf(0.07135482f, t, 1.5957691f);
    return z / (1.f + __expf(-u));
}

// fragment-major weight load: wave reads contiguous 1KB (tile*1024B + lane*16B)
__device__ __forceinline__ bf16x8 ldfrag(const short* base, int tile, int lane) {
    return *reinterpret_cast<const bf16x8*>(base + ((tile << 6) + lane) * 8);
}

// ---------- prep: weights -> bf16 fragment-major; rel bias pre-scaled by SCALE*log2e ----------
__global__ void prep_kernel(const float* __restrict__ wqkv, const float* __restrict__ wout,
                            const float* __restrict__ w1,   const float* __restrict__ w2,
                            const float* __restrict__ rel_bias, char* __restrict__ ws)
{
    short* wqkvb = (short*)ws;                 // 36864 elems, tiles r<24, c<3
    short* woutb = (short*)(ws + 73728);       // 12288, tiles r<6, c<4
    short* w1b   = (short*)(ws + 98304);       // 36864, tiles r<24, c<3
    short* w2b   = (short*)(ws + 172032);      // 36864, tiles r<6, c<12
    float* biasp = (float*)(ws + 245760);      // [4][49][64] fp32, *SCALE*LOG2E, key-padded
    const int idx = blockIdx.x * 256 + threadIdx.x;
    if (idx < 36864) {
        const int tile = idx >> 9, lane = (idx >> 3) & 63, j = idx & 7;
        const int r = tile / 3, c = tile % 3;
        wqkvb[idx] = f2bf(wqkv[(r*16 + (lane & 15))*96 + c*32 + (lane >> 4)*8 + j]);
    } else if (idx < 49152) {
        const int t = idx - 36864;
        const int tile = t >> 9, lane = (t >> 3) & 63, j = t & 7;
        const int r = tile >> 2, c = tile & 3;
        woutb[t] = f2bf(wout[(r*16 + (lane & 15))*128 + c*32 + (lane >> 4)*8 + j]);
    } else if (idx < 86016) {
        const int t = idx - 49152;
        const int tile = t >> 9, lane = (t >> 3) & 63, j = t & 7;
        const int r = tile / 3, c = tile % 3;
        w1b[t] = f2bf(w1[(r*16 + (lane & 15))*96 + c*32 + (lane >> 4)*8 + j]);
    } else if (idx < 122880) {
        const int t = idx - 86016;
        const int tile = t >> 9, lane = (t >> 3) & 63, j = t & 7;
        const int r = tile / 12, c = tile % 12;
        w2b[t] = f2bf(w2[(r*16 + (lane & 15))*384 + c*32 + (lane >> 4)*8 + j]);
    } else if (idx < 135424) {
        const int t = idx - 122880;
        const int h = t / 3136, r = t % 3136, q = r / 64, k = r % 64;
        float v = 0.f;
        if (k < 49) {
            const int rel = (q/7 - k/7 + 6) * 13 + (q%7 - k%7 + 6);
            v = rel_bias[rel * 4 + h] * SCALE * LOG2E;   // exp2-domain
        }
        biasp[t] = v;
    }
}

// ---------- fused kernel (R19 structure + exp2 softmax + truncating conversions) ----------
// LDS pool (50176 B); hs and qk DISJOINT:
//   hs[64][104]   [0,13312)  |  qk[4][64][QKS] [13312,50176)  wave-private
//   os[64][OSS]   [13312,30720) (aliases qk; gated by b3/b4)
//   h2[64][104]   [0,13312)  |  ts[64][TSS] [13312,38912) rows wave-private in FFN
// 4 barriers total (b1,b3,b4,b6); FFN barrier-free via row partitioning (R19).
__global__ __launch_bounds__(256, 3) void fused_kernel(
    const float* __restrict__ x, const char* __restrict__ ws,
    const float* __restrict__ b_out, const float* __restrict__ ln1_g,
    const float* __restrict__ ln1_b, const float* __restrict__ ln2_g,
    const float* __restrict__ ln2_b, const float* __restrict__ b1,
    const float* __restrict__ b2, float* __restrict__ y)
{
    __shared__ __align__(16) char pool[50176];
    short* hs = (short*)pool;
    short* qk = (short*)(pool + 13312);
    short* os = (short*)(pool + 13312);
    short* h2 = (short*)pool;
    short* ts = (short*)(pool + 13312);

    const short* wqkvb = (const short*)ws;
    const short* woutb = (const short*)(ws + 73728);
    const short* w1b   = (const short*)(ws + 98304);
    const short* w2b   = (const short*)(ws + 172032);
    const float* biasp = (const float*)(ws + 245760);

    const int tid = threadIdx.x;
    const int wv  = tid >> 6;
    const int lane = tid & 63;
    const int l15 = tid & 15;
    const int l4  = (tid & 63) >> 4;
    const int wid = blockIdx.x;
    const int b = wid >> 10, xr = (wid >> 5) & 31, yr = wid & 31;
    const int qkbase = wv * 64 * QKS;

    // ---- LN1: 4 threads per row, packed u32 stores ----
    if (tid < 196) {
        const int i = tid >> 2, g = tid & 3;
        const float* xp = x + ((size_t)b * NTOK + (size_t)(xr*7 + i/7) * IMG + (yr*7 + i%7)) * DIM + g*24;
        float v[24]; float s = 0.f, s2 = 0.f;
        #pragma unroll
        for (int c = 0; c < 6; ++c) {
            const float4 t4 = *reinterpret_cast<const float4*>(xp + c*4);
            v[c*4+0]=t4.x; v[c*4+1]=t4.y; v[c*4+2]=t4.z; v[c*4+3]=t4.w;
            s  += t4.x + t4.y + t4.z + t4.w;
            s2 += t4.x*t4.x + t4.y*t4.y + t4.z*t4.z + t4.w*t4.w;
        }
        s  += __shfl_xor(s, 1);  s  += __shfl_xor(s, 2);
        s2 += __shfl_xor(s2, 1); s2 += __shfl_xor(s2, 2);
        const float mu = s * (1.f/96.f);
        const float rs = rsqrtf(s2 * (1.f/96.f) - mu*mu + 1e-5f);
        #pragma unroll
        for (int c = 0; c < 12; ++c) {
            const int d = g*24 + c*2;
            const float a0 = (v[c*2+0] - mu) * rs * ln1_g[d]   + ln1_b[d];
            const float a1 = (v[c*2+1] - mu) * rs * ln1_g[d+1] + ln1_b[d+1];
            *reinterpret_cast<unsigned*>(&hs[i*104 + d]) = pktrunc(a0, a1);
        }
    }
    for (int idx = tid; idx < 780; idx += 256)
        *reinterpret_cast<unsigned*>(&hs[49*104 + idx*2]) = 0;
    __syncthreads();   // b1: hs ready

    // ---- qkv pass A: q,k (acc[4][4]) -> wave-private LDS, truncating stores ----
    {
        f32x4 acc[4][4];
        #pragma unroll
        for (int nt = 0; nt < 4; ++nt)
            #pragma unroll
            for (int mt = 0; mt < 4; ++mt)
                acc[nt][mt] = (f32x4){0.f,0.f,0.f,0.f};
        #pragma unroll
        for (int k3 = 0; k3 < 3; ++k3) {
            bf16x8 a4[4];
            #pragma unroll
            for (int mt = 0; mt < 4; ++mt)
                a4[mt] = *reinterpret_cast<const bf16x8*>(&hs[(mt*16 + l15)*104 + k3*32 + l4*8]);
            #pragma unroll
            for (int nt = 0; nt < 4; ++nt) {
                const int r = (nt < 2) ? wv*2 + nt : 8 + wv*2 + (nt-2);
                const bf16x8 bfr = ldfrag(wqkvb, r*3 + k3, lane);
                #pragma unroll
                for (int mt = 0; mt < 4; ++mt)
                    acc[nt][mt] = MFMA16(a4[mt], bfr, acc[nt][mt]);
            }
        }
        #pragma unroll
        for (int nt = 0; nt < 4; ++nt) {
            const int col0 = nt*16;
            #pragma unroll
            for (int mt = 0; mt < 4; ++mt)
                #pragma unroll
                for (int rg = 0; rg < 4; ++rg)
                    qk[qkbase + (mt*16 + l4*4 + rg)*QKS + col0 + l15] = bftrunc(acc[nt][mt][rg]);
        }
    }

    // ---- qkv pass B: v (acc[2][4]) -> vfrag registers ----
    u32x4 vfrag[2][2];
    {
        f32x4 accv[2][4];
        #pragma unroll
        for (int nv = 0; nv < 2; ++nv)
            #pragma unroll
            for (int mt = 0; mt < 4; ++mt)
                accv[nv][mt] = (f32x4){0.f,0.f,0.f,0.f};
        #pragma unroll
        for (int k3 = 0; k3 < 3; ++k3) {
            bf16x8 a4[4];
            #pragma unroll
            for (int mt = 0; mt < 4; ++mt)
                a4[mt] = *reinterpret_cast<const bf16x8*>(&hs[(mt*16 + l15)*104 + k3*32 + l4*8]);
            #pragma unroll
            for (int nv = 0; nv < 2; ++nv) {
                const bf16x8 bfr = ldfrag(wqkvb, (16 + wv*2 + nv)*3 + k3, lane);
                #pragma unroll
                for (int mt = 0; mt < 4; ++mt)
                    accv[nv][mt] = MFMA16(a4[mt], bfr, accv[nv][mt]);
            }
        }
        #pragma unroll
        for (int md = 0; md < 2; ++md)
            #pragma unroll
            for (int kst = 0; kst < 2; ++kst)
                vfrag[md][kst] = (u32x4){
                    pktrunc(accv[md][2*kst  ][0], accv[md][2*kst  ][1]),
                    pktrunc(accv[md][2*kst  ][2], accv[md][2*kst  ][3]),
                    pktrunc(accv[md][2*kst+1][0], accv[md][2*kst+1][1]),
                    pktrunc(accv[md][2*kst+1][2], accv[md][2*kst+1][3])};
    }
    // no barrier: qk store->read is same-wave

    // ---- S^T = K @ Q^T ----
    f32x4 st[4][4];
    {
        bf16x8 kf[4], qf[4];
        #pragma unroll
        for (int mt = 0; mt < 4; ++mt)
            kf[mt] = *reinterpret_cast<const bf16x8*>(&qk[qkbase + (mt*16 + l15)*QKS + 32 + l4*8]);
        #pragma unroll
        for (int nt = 0; nt < 4; ++nt)
            qf[nt] = *reinterpret_cast<const bf16x8*>(&qk[qkbase + (nt*16 + l15)*QKS + l4*8]);
        #pragma unroll
        for (int mt = 0; mt < 4; ++mt)
            #pragma unroll
            for (int nt = 0; nt < 4; ++nt)
                st[mt][nt] = MFMA16(kf[mt], qf[nt], ((f32x4){0.f,0.f,0.f,0.f}));
    }
    __syncthreads();   // b3

    // ---- softmax in exp2 domain (scores pre-scaled by log2e) ----
    unsigned pk[4][4][2];
    #pragma unroll
    for (int nq = 0; nq < 4; ++nq) {
        const int qc = (nq*16 + l15) < WT ? (nq*16 + l15) : 48;
        const float* bp = biasp + (wv*49 + qc)*64;
        float v[13];
        #pragma unroll
        for (int mk = 0; mk < 3; ++mk) {
            const float4 b4 = *reinterpret_cast<const float4*>(&bp[mk*16 + l4*4]);
            v[mk*4+0] = fmaf(st[mk][nq][0], SCL2, b4.x);
            v[mk*4+1] = fmaf(st[mk][nq][1], SCL2, b4.y);
            v[mk*4+2] = fmaf(st[mk][nq][2], SCL2, b4.z);
            v[mk*4+3] = fmaf(st[mk][nq][3], SCL2, b4.w);
        }
        v[12] = (l4 == 0) ? fmaf(st[3][nq][0], SCL2, bp[48]) : -1e30f;
        float mx = v[0];
        #pragma unroll
        for (int t = 1; t < 13; ++t) mx = fmaxf(mx, v[t]);
        mx = fmaxf(mx, __shfl_xor(mx, 16));
        mx = fmaxf(mx, __shfl_xor(mx, 32));
        float sum = 0.f;
        #pragma unroll
        for (int t = 0; t < 13; ++t) { v[t] = exp2f(v[t] - mx); sum += v[t]; }
        sum += __shfl_xor(sum, 16);
        sum += __shfl_xor(sum, 32);
        const float inv = 1.f / sum;
        #pragma unroll
        for (int mk = 0; mk < 3; ++mk) {
            pk[nq][mk][0] = pktrunc(v[mk*4+0]*inv, v[mk*4+1]*inv);
            pk[nq][mk][1] = pktrunc(v[mk*4+2]*inv, v[mk*4+3]*inv);
        }
        pk[nq][3][0] = pktrunc(v[12]*inv, 0.f);
        pk[nq][3][1] = 0u;
    }

    // ---- PV: o^T = V^T @ P^T — register operands ----
    {
        f32x4 oc[2][4];
        #pragma unroll
        for (int md = 0; md < 2; ++md)
            #pragma unroll
            for (int nq = 0; nq < 4; ++nq)
                oc[md][nq] = (f32x4){0.f,0.f,0.f,0.f};
        #pragma unroll
        for (int kst = 0; kst < 2; ++kst) {
            #pragma unroll
            for (int nq = 0; nq < 4; ++nq) {
                const bf16x8 bp8 = __builtin_bit_cast(bf16x8,
                    (u32x4){pk[nq][2*kst][0], pk[nq][2*kst][1], pk[nq][2*kst+1][0], pk[nq][2*kst+1][1]});
                #pragma unroll
                for (int md = 0; md < 2; ++md)
                    oc[md][nq] = MFMA16(__builtin_bit_cast(bf16x8, vfrag[md][kst]), bp8, oc[md][nq]);
            }
        }
        #pragma unroll
        for (int md = 0; md < 2; ++md)
            #pragma unroll
            for (int nq = 0; nq < 4; ++nq) {
                const unsigned lo = pktrunc(oc[md][nq][0], oc[md][nq][1]);
                const unsigned hi = pktrunc(oc[md][nq][2], oc[md][nq][3]);
                *reinterpret_cast<unsigned long long*>(
                    &os[(nq*16 + l15)*OSS + wv*32 + md*16 + l4*4]) =
                    ((unsigned long long)hi << 32) | lo;
            }
    }

    // ---- prefetches ----
    float xres[6][4];
    #pragma unroll
    for (int nt = 0; nt < 6; ++nt)
        #pragma unroll
        for (int rg = 0; rg < 4; ++rg) {
            const int tok = wv*16 + l4*4 + rg;
            const int tokc = tok < WT ? tok : 48;
            xres[nt][rg] = x[((size_t)b * NTOK + (size_t)(xr*7 + tokc/7) * IMG + (yr*7 + tokc%7)) * DIM + nt*16 + l15];
        }
    bf16x8 wofr[4][3];
    float bo6[6], g6[6], be6[6], b26[6];
    #pragma unroll
    for (int nt = 0; nt < 6; ++nt) {
        bo6[nt] = b_out[nt*16 + l15];
        g6[nt]  = ln2_g[nt*16 + l15];
        be6[nt] = ln2_b[nt*16 + l15];
        b26[nt] = b2[nt*16 + l15];
    }
    #pragma unroll
    for (int nt = 0; nt < 3; ++nt)
        #pragma unroll
        for (int kst = 0; kst < 4; ++kst)
            wofr[kst][nt] = ldfrag(woutb, nt*4 + kst, lane);
    __syncthreads();   // b4: os ready

    // ---- proj ----
    float yreg[6][4];
    {
        bf16x8 afr[4];
        #pragma unroll
        for (int kst = 0; kst < 4; ++kst)
            afr[kst] = *reinterpret_cast<const bf16x8*>(&os[(wv*16 + l15)*OSS + kst*32 + l4*8]);
        #pragma unroll
        for (int nt = 0; nt < 6; ++nt) {
            f32x4 acc = (f32x4){0.f,0.f,0.f,0.f};
            #pragma unroll
            for (int kst = 0; kst < 4; ++kst) {
                const bf16x8 wfr = (nt < 3) ? wofr[kst][nt] : ldfrag(woutb, nt*4 + kst, lane);
                acc = MFMA16(afr[kst], wfr, acc);
            }
            #pragma unroll
            for (int rg = 0; rg < 4; ++rg)
                yreg[nt][rg] = acc[rg] + bo6[nt] + xres[nt][rg];
        }
    }

    // ---- LN2 in-register, truncating h2 stores ----
    float mu4[4], rs4[4];
    #pragma unroll
    for (int rg = 0; rg < 4; ++rg) {
        float s = 0.f, s2 = 0.f;
        #pragma unroll
        for (int nt = 0; nt < 6; ++nt) { const float v = yreg[nt][rg]; s += v; s2 += v*v; }
        s  += __shfl_xor(s, 1);  s  += __shfl_xor(s, 2);  s  += __shfl_xor(s, 4);  s  += __shfl_xor(s, 8);
        s2 += __shfl_xor(s2, 1); s2 += __shfl_xor(s2, 2); s2 += __shfl_xor(s2, 4); s2 += __shfl_xor(s2, 8);
        const float m = s * (1.f/96.f);
        mu4[rg] = m;
        rs4[rg] = rsqrtf(s2 * (1.f/96.f) - m*m + 1e-5f);
    }
    #pragma unroll
    for (int nt = 0; nt < 6; ++nt)
        #pragma unroll
        for (int rg = 0; rg < 4; ++rg)
            h2[(wv*16 + l4*4 + rg)*104 + nt*16 + l15] =
                bftrunc((yreg[nt][rg] - mu4[rg]) * rs4[rg] * g6[nt] + be6[nt]);
    __syncthreads();   // b6: h2 ready; os fully consumed -> ts may overwrite

    // ---- FFN: row-partitioned, barrier-free (R19), truncating ts stores ----
    f32x4 acc2[6];
    #pragma unroll
    for (int nt = 0; nt < 6; ++nt) acc2[nt] = (f32x4){0.f,0.f,0.f,0.f};

    #pragma unroll
    for (int al = 0; al < 2; ++al) {
        bf16x8 af[3];
        #pragma unroll
        for (int k3 = 0; k3 < 3; ++k3)
            af[k3] = *reinterpret_cast<const bf16x8*>(&h2[(wv*16 + l15)*104 + k3*32 + l4*8]);
        #pragma unroll
        for (int n12 = 0; n12 < 12; ++n12) {
            f32x4 a1 = (f32x4){0.f,0.f,0.f,0.f};
            #pragma unroll
            for (int k3 = 0; k3 < 3; ++k3)
                a1 = MFMA16(af[k3], ldfrag(w1b, (al*12 + n12)*3 + k3, lane), a1);
            const float bb = b1[al*192 + n12*16 + l15];
            #pragma unroll
            for (int rg = 0; rg < 4; ++rg)
                ts[(wv*16 + l4*4 + rg)*TSS + n12*16 + l15] = bftrunc(gelu_f(a1[rg] + bb));
        }
        bf16x8 at[6];
        #pragma unroll
        for (int kl = 0; kl < 6; ++kl)
            at[kl] = *reinterpret_cast<const bf16x8*>(&ts[(wv*16 + l15)*TSS + kl*32 + l4*8]);
        #pragma unroll
        for (int nt = 0; nt < 6; ++nt) {
            #pragma unroll
            for (int kl = 0; kl < 6; ++kl)
                acc2[nt] = MFMA16(at[kl], ldfrag(w2b, nt*12 + al*6 + kl, lane), acc2[nt]);
        }
    }

    // ---- final write ----
    #pragma unroll
    for (int nt = 0; nt < 6; ++nt)
        #pragma unroll
        for (int rg = 0; rg < 4; ++rg) {
            const int tok = wv*16 + l4*4 + rg;
            if (tok < WT) {
                const size_t gi = ((size_t)b * NTOK + (size_t)(xr*7 + tok/7) * IMG + (yr*7 + tok%7)) * DIM + nt*16 + l15;
                y[gi] = acc2[nt][rg] + b26[nt] + yreg[nt][rg];
            }
        }
}

extern "C" void kernel_launch(void* const* d_in, const int* in_sizes, int n_in,
                              void* d_out, int out_size, void* d_ws, size_t ws_size,
                              hipStream_t stream) {
    const float* x     = (const float*)d_in[0];
    const float* w_qkv = (const float*)d_in[1];
    const float* w_out = (const float*)d_in[2];
    const float* b_out = (const float*)d_in[3];
    const float* rel_b = (const float*)d_in[4];
    const float* ln1_g = (const float*)d_in[5];
    const float* ln1_b = (const float*)d_in[6];
    const float* ln2_g = (const float*)d_in[7];
    const float* ln2_b = (const float*)d_in[8];
    const float* w1    = (const float*)d_in[9];
    const float* b1    = (const float*)d_in[10];
    const float* w2    = (const float*)d_in[11];
    const float* b2    = (const float*)d_in[12];
    float* y = (float*)d_out;
    char* ws = (char*)d_ws;

    prep_kernel<<<529, 256, 0, stream>>>(w_qkv, w_out, w1, w2, rel_b, ws);
    fused_kernel<<<NB * 32 * 32, 256, 0, stream>>>(x, ws, b_out, ln1_g, ln1_b,
                                                   ln2_g, ln2_b, b1, b2, y);
}